// Round 4
// baseline (1221.924 us; speedup 1.0000x reference)
//
#include <hip/hip_runtime.h>
#include <math.h>

typedef unsigned short u16;
typedef __attribute__((ext_vector_type(4))) float f32x4;
typedef __attribute__((ext_vector_type(8))) __bf16 bf16x8;
typedef __attribute__((ext_vector_type(8))) u16 u16x8;
typedef __attribute__((ext_vector_type(4))) u16 u16x4;

__device__ __forceinline__ float bf2f(u16 v) {
    unsigned int u = ((unsigned int)v) << 16;
    return __builtin_bit_cast(float, u);
}
__device__ __forceinline__ u16 f2bf(float f) {
    unsigned int x = __builtin_bit_cast(unsigned int, f);
    x += 0x7fffu + ((x >> 16) & 1u);   // RNE
    return (u16)(x >> 16);
}

__device__ __forceinline__ void load_lds16(const u16* g, u16* l) {
    __builtin_amdgcn_global_load_lds((const __attribute__((address_space(1))) void*)g,
                                     (__attribute__((address_space(3))) void*)l, 16, 0, 0);
}

// ---------------------------------------------------------------------------
// f32 -> bf16 weight conversion
// ---------------------------------------------------------------------------
__global__ __launch_bounds__(256) void cvt_kernel(const float* __restrict__ in,
                                                  u16* __restrict__ out, int n)
{
    const int i = (blockIdx.x * 256 + threadIdx.x) * 4;
    if (i >= n) return;
    const float4 f = *(const float4*)(in + i);
    u16x4 o;
    o[0] = f2bf(f.x); o[1] = f2bf(f.y); o[2] = f2bf(f.z); o[3] = f2bf(f.w);
    *(u16x4*)(out + i) = o;
}

// ---------------------------------------------------------------------------
// GEMM: C[M][N] = epi( A[M][K](bf16) * Wb[N][K](bf16)^T + bias[N](f32) )
// EPI 0: qkv scatter -> Q (bh,t,d), K (bh,t,d), Vt (bh,d,t); rows offset mbase
// EPI 1: + residual -> O0   (RES=1: f32 residual, RES=2: bf16 residual)
// EPI 2: exact GELU -> O0
// OF32: O0 is float* (final output); else u16* (bf16)
// ---------------------------------------------------------------------------
template<int EPI, int RES, bool OF32>
__global__ __launch_bounds__(256) void gemm_bt(
    const u16* __restrict__ A, const u16* __restrict__ W,
    const float* __restrict__ bias,
    const float* __restrict__ resf, const u16* __restrict__ resb,
    void* __restrict__ O0v, u16* __restrict__ O1, u16* __restrict__ O2,
    int M, int N, int K, int mbase)
{
    __shared__ u16 As[128 * 32];
    __shared__ u16 Bs[128 * 32];
    const int tid  = threadIdx.x;
    const int wave = tid >> 6;
    const int lane = tid & 63;
    const int m0   = blockIdx.y * 128;
    const int n0   = blockIdx.x * 128;
    const int wm   = (wave >> 1) * 64;
    const int wn   = (wave & 1) * 64;

    const int srow = lane >> 2;
    const int scol = (lane & 3) * 8;
    const u16* ag0 = A + (size_t)(m0 + wave * 16 + srow) * K + scol;
    const u16* ag1 = ag0 + (size_t)64 * K;
    const u16* bg0 = W + (size_t)(n0 + wave * 16 + srow) * K + scol;
    const u16* bg1 = bg0 + (size_t)64 * K;
    u16* as0 = As + (wave * 16) * 32;
    u16* as1 = As + (64 + wave * 16) * 32;
    u16* bs0 = Bs + (wave * 16) * 32;
    u16* bs1 = Bs + (64 + wave * 16) * 32;

    const int colq = lane & 15;
    const int quad = lane >> 4;

    f32x4 acc[4][4] = {};

    for (int k0 = 0; k0 < K; k0 += 32) {
        if (k0) __syncthreads();
        load_lds16(ag0 + k0, as0);
        load_lds16(ag1 + k0, as1);
        load_lds16(bg0 + k0, bs0);
        load_lds16(bg1 + k0, bs1);
        __syncthreads();
        bf16x8 a[4], b[4];
#pragma unroll
        for (int i = 0; i < 4; ++i) {
            a[i] = *(const bf16x8*)(As + (wm + i * 16 + colq) * 32 + quad * 8);
            b[i] = *(const bf16x8*)(Bs + (wn + i * 16 + colq) * 32 + quad * 8);
        }
#pragma unroll
        for (int mi = 0; mi < 4; ++mi)
#pragma unroll
            for (int ni = 0; ni < 4; ++ni)
                acc[mi][ni] = __builtin_amdgcn_mfma_f32_16x16x32_bf16(a[mi], b[ni], acc[mi][ni], 0, 0, 0);
    }

    // epilogue: C row = quad*4+i, col = lane&15 (m89-verified C/D layout)
#pragma unroll
    for (int ni = 0; ni < 4; ++ni) {
        const int c = n0 + wn + ni * 16 + colq;
        const float bz = bias[c];
#pragma unroll
        for (int mi = 0; mi < 4; ++mi) {
#pragma unroll
            for (int i = 0; i < 4; ++i) {
                const int r = m0 + wm + mi * 16 + quad * 4 + i;
                float v = acc[mi][ni][i] + bz;
                if constexpr (EPI == 0) {
                    const int which = c >> 10;          // (3, h, hd) split of 3C axis
                    const int head  = (c >> 6) & 15;
                    const int d     = c & 63;
                    const int rg    = mbase + r;
                    const int bb    = rg >> 12;
                    const int t     = rg & 4095;
                    const int bh    = bb * 16 + head;
                    const u16 val = f2bf(v);
                    if (which == 0)      ((u16*)O0v)[((size_t)bh * 4096 + t) * 64 + d] = val; // Q
                    else if (which == 1) O1[((size_t)bh * 4096 + t) * 64 + d] = val;          // K
                    else                 O2[((size_t)bh * 64 + d) * 4096 + t] = val;          // Vt
                } else {
                    const size_t idx = (size_t)r * N + c;
                    if constexpr (RES == 1) v += resf[idx];
                    if constexpr (RES == 2) v += bf2f(resb[idx]);
                    if constexpr (EPI == 2) v = 0.5f * v * (1.0f + erff(v * 0.70710678118654752f));
                    if constexpr (OF32) ((float*)O0v)[idx] = v;
                    else                ((u16*)O0v)[idx] = f2bf(v);
                }
            }
        }
    }
}

// ---------------------------------------------------------------------------
// LayerNorm: one wave per row of 1024. F32IN: x is f32 (LN1); else bf16 (LN2).
// ---------------------------------------------------------------------------
template<bool F32IN>
__global__ __launch_bounds__(256) void ln_kernel(
    const void* __restrict__ xin, const float* __restrict__ w,
    const float* __restrict__ b, u16* __restrict__ out)
{
    const int wave = threadIdx.x >> 6, lane = threadIdx.x & 63;
    const size_t row = (size_t)blockIdx.x * 4 + wave;
    float v[16];
    if constexpr (F32IN) {
        const float* xr = (const float*)xin + row * 1024 + lane * 16;
#pragma unroll
        for (int j = 0; j < 4; ++j) {
            const float4 f = *(const float4*)(xr + j * 4);
            v[j * 4 + 0] = f.x; v[j * 4 + 1] = f.y; v[j * 4 + 2] = f.z; v[j * 4 + 3] = f.w;
        }
    } else {
        const u16* xr = (const u16*)xin + row * 1024 + lane * 16;
        u16x8 xa = *(const u16x8*)xr;
        u16x8 xb = *(const u16x8*)(xr + 8);
#pragma unroll
        for (int i = 0; i < 8; ++i) { v[i] = bf2f(xa[i]); v[8 + i] = bf2f(xb[i]); }
    }
    float s = 0.f, s2 = 0.f;
#pragma unroll
    for (int i = 0; i < 16; ++i) { s += v[i]; s2 += v[i] * v[i]; }
#pragma unroll
    for (int m = 32; m >= 1; m >>= 1) { s += __shfl_xor(s, m, 64); s2 += __shfl_xor(s2, m, 64); }
    const float mu  = s * (1.0f / 1024.0f);
    const float var = s2 * (1.0f / 1024.0f) - mu * mu;
    const float rs  = rsqrtf(var + 1e-5f);
    const float* wp = w + lane * 16;
    const float* bp = b + lane * 16;
    u16x8 oa, ob;
#pragma unroll
    for (int i = 0; i < 8; ++i) {
        oa[i] = f2bf((v[i]     - mu) * rs * wp[i]     + bp[i]);
        ob[i] = f2bf((v[8 + i] - mu) * rs * wp[8 + i] + bp[8 + i]);
    }
    u16* orow = out + row * 1024 + lane * 16;
    *(u16x8*)orow       = oa;
    *(u16x8*)(orow + 8) = ob;
}

// ---------------------------------------------------------------------------
// Local attention: grid (N/64, B*h); wave = 16 q-rows; full 384-key S in regs.
// ---------------------------------------------------------------------------
__global__ __launch_bounds__(256) void attn_kernel(
    const u16* __restrict__ Q, const u16* __restrict__ Kb,
    const u16* __restrict__ Vt, u16* __restrict__ out)
{
    __shared__ u16 Ps[4][16][392];   // per-wave P tile [qrow][key], +8 pad
    const int wave = threadIdx.x >> 6;
    const int lane = threadIdx.x & 63;
    const int colq = lane & 15;
    const int quad = lane >> 4;
    const int bh   = blockIdx.y;
    const int tb   = blockIdx.x;
    const int qrow0 = tb * 64 + wave * 16;
    const int nb    = tb >> 1;            // 128-wide attention bucket index
    const int key0  = nb * 128 - 128;
    const int nt_lo = (nb == 0) ? 8 : 0;
    const int nt_hi = (nb == 31) ? 16 : 24;

    const u16* qp = Q + ((size_t)bh * 4096 + qrow0 + colq) * 64 + quad * 8;
    bf16x8 aq0 = *(const bf16x8*)qp;
    bf16x8 aq1 = *(const bf16x8*)(qp + 32);

    f32x4 s[24];
#pragma unroll
    for (int nt = 0; nt < 24; ++nt) s[nt] = (f32x4){-1e30f, -1e30f, -1e30f, -1e30f};
#pragma unroll
    for (int nt = 0; nt < 24; ++nt) {
        if (nt >= nt_lo && nt < nt_hi) {
            const u16* kp = Kb + ((size_t)bh * 4096 + key0 + nt * 16 + colq) * 64 + quad * 8;
            bf16x8 b0 = *(const bf16x8*)kp;
            bf16x8 b1 = *(const bf16x8*)(kp + 32);
            f32x4 z = {0.f, 0.f, 0.f, 0.f};
            z = __builtin_amdgcn_mfma_f32_16x16x32_bf16(aq0, b0, z, 0, 0, 0);
            z = __builtin_amdgcn_mfma_f32_16x16x32_bf16(aq1, b1, z, 0, 0, 0);
            s[nt] = z;
        }
    }

    float mrow[4] = {-1e30f, -1e30f, -1e30f, -1e30f};
#pragma unroll
    for (int nt = 0; nt < 24; ++nt)
        if (nt >= nt_lo && nt < nt_hi)
#pragma unroll
            for (int i = 0; i < 4; ++i) mrow[i] = fmaxf(mrow[i], s[nt][i]);
#pragma unroll
    for (int i = 0; i < 4; ++i)
#pragma unroll
        for (int m = 8; m >= 1; m >>= 1) mrow[i] = fmaxf(mrow[i], __shfl_xor(mrow[i], m, 64));

    float lrow[4] = {0.f, 0.f, 0.f, 0.f};
#pragma unroll
    for (int nt = 0; nt < 24; ++nt) {
        if (nt >= nt_lo && nt < nt_hi) {
#pragma unroll
            for (int i = 0; i < 4; ++i) {
                const float p = __expf((s[nt][i] - mrow[i]) * 0.125f);  // scale = hd^-0.5
                lrow[i] += p;
                Ps[wave][quad * 4 + i][nt * 16 + colq] = f2bf(p);
            }
        }
    }
#pragma unroll
    for (int i = 0; i < 4; ++i)
#pragma unroll
        for (int m = 8; m >= 1; m >>= 1) lrow[i] += __shfl_xor(lrow[i], m, 64);
    __syncthreads();

    const int ks_lo = nt_lo >> 1, ks_hi = nt_hi >> 1;
    f32x4 o[4] = {};
#pragma unroll
    for (int ks = 0; ks < 12; ++ks) {
        if (ks >= ks_lo && ks < ks_hi) {
            bf16x8 ap = *(const bf16x8*)&Ps[wave][colq][ks * 32 + quad * 8];
#pragma unroll
            for (int dt = 0; dt < 4; ++dt) {
                const u16* vp = Vt + ((size_t)bh * 64 + dt * 16 + colq) * 4096 + key0 + ks * 32 + quad * 8;
                bf16x8 bv = *(const bf16x8*)vp;
                o[dt] = __builtin_amdgcn_mfma_f32_16x16x32_bf16(ap, bv, o[dt], 0, 0, 0);
            }
        }
    }

    const int bb = bh >> 4, hh = bh & 15;
#pragma unroll
    for (int i = 0; i < 4; ++i) {
        const float inv = 1.0f / fmaxf(lrow[i], 1e-20f);
        const int t = qrow0 + quad * 4 + i;
        u16* op = out + ((size_t)(bb * 4096 + t)) * 1024 + hh * 64;
#pragma unroll
        for (int dt = 0; dt < 4; ++dt) op[dt * 16 + colq] = f2bf(o[dt][i] * inv);
    }
}

// ---------------------------------------------------------------------------
extern "C" void kernel_launch(void* const* d_in, const int* in_sizes, int n_in,
                              void* d_out, int out_size, void* d_ws, size_t ws_size,
                              hipStream_t stream)
{
    // Inputs f32 (per reference); OUTPUT f32 (reference returns jnp.float32).
    const float* x      = (const float*)d_in[0];
    const float* ln1_w  = (const float*)d_in[1];
    const float* ln1_b  = (const float*)d_in[2];
    const float* qkv_w  = (const float*)d_in[3];
    const float* qkv_b  = (const float*)d_in[4];
    const float* proj_w = (const float*)d_in[5];
    const float* proj_b = (const float*)d_in[6];
    const float* ln2_w  = (const float*)d_in[7];
    const float* ln2_b  = (const float*)d_in[8];
    const float* fc1_w  = (const float*)d_in[9];
    const float* fc1_b  = (const float*)d_in[10];
    const float* fc2_w  = (const float*)d_in[11];
    const float* fc2_b  = (const float*)d_in[12];
    float* outp = (float*)d_out;

    // Workspace: 4 regions x 33,554,432 B = 134,217,728 B (proven available).
    if (ws_size < 134217728u) return;
    char* ws = (char*)d_ws;
    u16* R0 = (u16*)(ws);               // xn-chunk + qkv_wbf -> attn_out -> fc1/fc2 wbf
    u16* R1 = (u16*)(ws + 33554432);    // Q  -> x2
    u16* R2 = (u16*)(ws + 67108864);    // K  -> proj_wbf -> yn
    u16* R3 = (u16*)(ws + 100663296);   // Vt -> h-chunk

    u16* xnc    = R0;                   // 8192*1024 bf16
    u16* qkvwb  = R0 + 8388608;         // 3072*1024 bf16
    u16* Qb = R1, *Kb = R2, *Vtb = R3;
    u16* attn_o = R0;
    u16* projwb = R2;                   // K dead after attn
    u16* x2     = R1;                   // Q dead after attn
    u16* yn     = R2;                   // proj_wbf dead after proj
    u16* fc1wb  = R0;                   // attn_out dead after proj
    u16* fc2wb  = R0 + 4194304;
    u16* hb     = R3;                   // Vt dead after attn

    // 1. qkv_w f32 -> bf16
    cvt_kernel<<<3072, 256, 0, stream>>>(qkv_w, qkvwb, 3145728);
    // 2. LN1 + qkv GEMM in two M-chunks of 8192 rows
    for (int c = 0; c < 2; ++c) {
        ln_kernel<true><<<2048, 256, 0, stream>>>(x + (size_t)c * 8192 * 1024, ln1_w, ln1_b, xnc);
        gemm_bt<0, 0, false><<<dim3(24, 64), 256, 0, stream>>>(xnc, qkvwb, qkv_b, nullptr, nullptr,
                                                               Qb, Kb, Vtb, 8192, 3072, 1024, c * 8192);
    }
    // 3. local attention -> attn_out
    attn_kernel<<<dim3(64, 64), 256, 0, stream>>>(Qb, Kb, Vtb, attn_o);
    // 4. proj + residual(x, f32) -> x2 (bf16)
    cvt_kernel<<<1024, 256, 0, stream>>>(proj_w, projwb, 1048576);
    gemm_bt<1, 1, false><<<dim3(8, 128), 256, 0, stream>>>(attn_o, projwb, proj_b, x, nullptr,
                                                           x2, nullptr, nullptr, 16384, 1024, 1024, 0);
    // 5. LN2: x2 (bf16) -> yn
    ln_kernel<false><<<4096, 256, 0, stream>>>(x2, ln2_w, ln2_b, yn);
    // 6. FFN weights -> bf16
    cvt_kernel<<<4096, 256, 0, stream>>>(fc1_w, fc1wb, 4194304);
    cvt_kernel<<<4096, 256, 0, stream>>>(fc2_w, fc2wb, 4194304);
    // 7. FFN in 4 M-chunks of 4096 rows; h-chunk in R3; fc2 writes f32 output
    for (int ci = 0; ci < 4; ++ci) {
        const size_t off = (size_t)ci * 4096 * 1024;
        gemm_bt<2, 0, false><<<dim3(32, 32), 256, 0, stream>>>(yn + off, fc1wb, fc1_b, nullptr, nullptr,
                                                               hb, nullptr, nullptr, 4096, 4096, 1024, 0);
        gemm_bt<1, 2, true><<<dim3(8, 32), 256, 0, stream>>>(hb, fc2wb, fc2_b, nullptr, x2 + off,
                                                             outp + off, nullptr, nullptr, 4096, 1024, 4096, 0);
    }
}

// Round 5
// 1025.612 us; speedup vs baseline: 1.1914x; 1.1914x over previous
//
#include <hip/hip_runtime.h>
#include <math.h>

typedef unsigned short u16;
typedef __attribute__((ext_vector_type(4))) float f32x4;
typedef __attribute__((ext_vector_type(8))) __bf16 bf16x8;
typedef __attribute__((ext_vector_type(8))) u16 u16x8;
typedef __attribute__((ext_vector_type(4))) u16 u16x4;

__device__ __forceinline__ float bf2f(u16 v) {
    unsigned int u = ((unsigned int)v) << 16;
    return __builtin_bit_cast(float, u);
}
__device__ __forceinline__ u16 f2bf(float f) {
    unsigned int x = __builtin_bit_cast(unsigned int, f);
    x += 0x7fffu + ((x >> 16) & 1u);   // RNE
    return (u16)(x >> 16);
}

__device__ __forceinline__ void load_lds16(const u16* g, u16* l) {
    __builtin_amdgcn_global_load_lds((const __attribute__((address_space(1))) void*)g,
                                     (__attribute__((address_space(3))) void*)l, 16, 0, 0);
}

// ---------------------------------------------------------------------------
// f32 -> bf16 weight conversion
// ---------------------------------------------------------------------------
__global__ __launch_bounds__(256) void cvt_kernel(const float* __restrict__ in,
                                                  u16* __restrict__ out, int n)
{
    const int i = (blockIdx.x * 256 + threadIdx.x) * 4;
    if (i >= n) return;
    const float4 f = *(const float4*)(in + i);
    u16x4 o;
    o[0] = f2bf(f.x); o[1] = f2bf(f.y); o[2] = f2bf(f.z); o[3] = f2bf(f.w);
    *(u16x4*)(out + i) = o;
}

// ---------------------------------------------------------------------------
// GEMM: C[M][N] = epi( A[M][K](bf16) * Wb[N][K](bf16)^T + bias[N](f32) )
// EPI 0: qkv scatter -> Q (bh,t,d), K (bh,t,d), Vt (bh,d,t)
// EPI 1: + residual  (RES=1: f32 residual, RES=2: bf16 residual)
// EPI 2: exact GELU
// OF32: O0 is float* (final output); else u16* (bf16)
// ---------------------------------------------------------------------------
template<int EPI, int RES, bool OF32>
__global__ __launch_bounds__(256) void gemm_bt(
    const u16* __restrict__ A, const u16* __restrict__ W,
    const float* __restrict__ bias,
    const float* __restrict__ resf, const u16* __restrict__ resb,
    void* __restrict__ O0v, u16* __restrict__ O1, u16* __restrict__ O2,
    int M, int N, int K, int mbase)
{
    __shared__ u16 As[128 * 32];
    __shared__ u16 Bs[128 * 32];
    const int tid  = threadIdx.x;
    const int wave = tid >> 6;
    const int lane = tid & 63;
    const int m0   = blockIdx.y * 128;
    const int n0   = blockIdx.x * 128;
    const int wm   = (wave >> 1) * 64;
    const int wn   = (wave & 1) * 64;

    const int srow = lane >> 2;
    const int scol = (lane & 3) * 8;
    const u16* ag0 = A + (size_t)(m0 + wave * 16 + srow) * K + scol;
    const u16* ag1 = ag0 + (size_t)64 * K;
    const u16* bg0 = W + (size_t)(n0 + wave * 16 + srow) * K + scol;
    const u16* bg1 = bg0 + (size_t)64 * K;
    u16* as0 = As + (wave * 16) * 32;
    u16* as1 = As + (64 + wave * 16) * 32;
    u16* bs0 = Bs + (wave * 16) * 32;
    u16* bs1 = Bs + (64 + wave * 16) * 32;

    const int colq = lane & 15;
    const int quad = lane >> 4;

    f32x4 acc[4][4] = {};

    for (int k0 = 0; k0 < K; k0 += 32) {
        if (k0) __syncthreads();
        load_lds16(ag0 + k0, as0);
        load_lds16(ag1 + k0, as1);
        load_lds16(bg0 + k0, bs0);
        load_lds16(bg1 + k0, bs1);
        __syncthreads();
        bf16x8 a[4], b[4];
#pragma unroll
        for (int i = 0; i < 4; ++i) {
            a[i] = *(const bf16x8*)(As + (wm + i * 16 + colq) * 32 + quad * 8);
            b[i] = *(const bf16x8*)(Bs + (wn + i * 16 + colq) * 32 + quad * 8);
        }
#pragma unroll
        for (int mi = 0; mi < 4; ++mi)
#pragma unroll
            for (int ni = 0; ni < 4; ++ni)
                acc[mi][ni] = __builtin_amdgcn_mfma_f32_16x16x32_bf16(a[mi], b[ni], acc[mi][ni], 0, 0, 0);
    }

    // epilogue: C row = quad*4+i, col = lane&15 (m89-verified C/D layout)
#pragma unroll
    for (int ni = 0; ni < 4; ++ni) {
        const int c = n0 + wn + ni * 16 + colq;
        const float bz = bias[c];
#pragma unroll
        for (int mi = 0; mi < 4; ++mi) {
#pragma unroll
            for (int i = 0; i < 4; ++i) {
                const int r = m0 + wm + mi * 16 + quad * 4 + i;
                float v = acc[mi][ni][i] + bz;
                if constexpr (EPI == 0) {
                    const int which = c >> 10;          // (3, h, hd) split of 3C axis
                    const int head  = (c >> 6) & 15;
                    const int d     = c & 63;
                    const int rg    = mbase + r;
                    const int bb    = rg >> 12;
                    const int t     = rg & 4095;
                    const int bh    = bb * 16 + head;
                    const u16 val = f2bf(v);
                    if (which == 0)      ((u16*)O0v)[((size_t)bh * 4096 + t) * 64 + d] = val; // Q
                    else if (which == 1) O1[((size_t)bh * 4096 + t) * 64 + d] = val;          // K
                    else                 O2[((size_t)bh * 64 + d) * 4096 + t] = val;          // Vt
                } else {
                    const size_t idx = (size_t)r * N + c;
                    if constexpr (RES == 1) v += resf[idx];
                    if constexpr (RES == 2) v += bf2f(resb[idx]);
                    if constexpr (EPI == 2) v = 0.5f * v * (1.0f + erff(v * 0.70710678118654752f));
                    if constexpr (OF32) ((float*)O0v)[idx] = v;
                    else                ((u16*)O0v)[idx] = f2bf(v);
                }
            }
        }
    }
}

// ---------------------------------------------------------------------------
// LayerNorm: one wave per row of 1024. F32IN: x is f32 (LN1); else bf16 (LN2).
// ---------------------------------------------------------------------------
template<bool F32IN>
__global__ __launch_bounds__(256) void ln_kernel(
    const void* __restrict__ xin, const float* __restrict__ w,
    const float* __restrict__ b, u16* __restrict__ out)
{
    const int wave = threadIdx.x >> 6, lane = threadIdx.x & 63;
    const size_t row = (size_t)blockIdx.x * 4 + wave;
    float v[16];
    if constexpr (F32IN) {
        const float* xr = (const float*)xin + row * 1024 + lane * 16;
#pragma unroll
        for (int j = 0; j < 4; ++j) {
            const float4 f = *(const float4*)(xr + j * 4);
            v[j * 4 + 0] = f.x; v[j * 4 + 1] = f.y; v[j * 4 + 2] = f.z; v[j * 4 + 3] = f.w;
        }
    } else {
        const u16* xr = (const u16*)xin + row * 1024 + lane * 16;
        u16x8 xa = *(const u16x8*)xr;
        u16x8 xb = *(const u16x8*)(xr + 8);
#pragma unroll
        for (int i = 0; i < 8; ++i) { v[i] = bf2f(xa[i]); v[8 + i] = bf2f(xb[i]); }
    }
    float s = 0.f, s2 = 0.f;
#pragma unroll
    for (int i = 0; i < 16; ++i) { s += v[i]; s2 += v[i] * v[i]; }
#pragma unroll
    for (int m = 32; m >= 1; m >>= 1) { s += __shfl_xor(s, m, 64); s2 += __shfl_xor(s2, m, 64); }
    const float mu  = s * (1.0f / 1024.0f);
    const float var = s2 * (1.0f / 1024.0f) - mu * mu;
    const float rs  = rsqrtf(var + 1e-5f);
    const float* wp = w + lane * 16;
    const float* bp = b + lane * 16;
    u16x8 oa, ob;
#pragma unroll
    for (int i = 0; i < 8; ++i) {
        oa[i] = f2bf((v[i]     - mu) * rs * wp[i]     + bp[i]);
        ob[i] = f2bf((v[8 + i] - mu) * rs * wp[8 + i] + bp[8 + i]);
    }
    u16* orow = out + row * 1024 + lane * 16;
    *(u16x8*)orow       = oa;
    *(u16x8*)(orow + 8) = ob;
}

// ---------------------------------------------------------------------------
// Local attention, flash-style over 2 key-chunks of 192.
// Grid: 4096 flat blocks, XCD-swizzled so same-bh adjacent-tb blocks share an
// XCD (L2 reuse of the 3x-overlapping K/V windows). Wave = 16 q-rows.
// Ps: 25.6 KB (pitch 200 u16 == 4 mod 32 words: bank-balanced b128 reads).
// ---------------------------------------------------------------------------
__global__ __launch_bounds__(256, 4) void attn_kernel(
    const u16* __restrict__ Q, const u16* __restrict__ Kb,
    const u16* __restrict__ Vt, u16* __restrict__ out)
{
    __shared__ u16 Ps[4][16 * 200];
    const int tid  = threadIdx.x;
    const int wave = tid >> 6;
    const int lane = tid & 63;
    const int colq = lane & 15;
    const int quad = lane >> 4;

    const int f   = blockIdx.x;            // 0..4095
    const int xcd = f & 7;
    const int s8  = f >> 3;                // 0..511
    const int bh  = s8 >> 3;               // 0..63
    const int tb  = (s8 & 7) + 8 * xcd;    // 0..63
    const int qrow0 = tb * 64 + wave * 16;
    const int nb    = tb >> 1;
    const int key0  = nb * 128 - 128;
    const int nt_lo = (nb == 0) ? 8 : 0;
    const int nt_hi = (nb == 31) ? 16 : 24;

    const u16* qp = Q + ((size_t)bh * 4096 + qrow0 + colq) * 64 + quad * 8;
    bf16x8 aq0 = *(const bf16x8*)qp;
    bf16x8 aq1 = *(const bf16x8*)(qp + 32);

    float m_i[4], l_i[4];
    f32x4 o[4] = {};
#pragma unroll
    for (int i = 0; i < 4; ++i) { m_i[i] = -3.0e38f; l_i[i] = 0.f; }

    u16* Psw = &Ps[wave][0];

#pragma unroll
    for (int c = 0; c < 2; ++c) {
        const int lo = (c == 0) ? nt_lo : 12;
        const int hi = (c == 0) ? ((nt_hi < 12) ? nt_hi : 12) : nt_hi;

        f32x4 sc[12];
#pragma unroll
        for (int j = 0; j < 12; ++j) sc[j] = (f32x4){0.f, 0.f, 0.f, 0.f};
#pragma unroll
        for (int j = 0; j < 12; ++j) {
            const int nt = c * 12 + j;
            if (nt >= lo && nt < hi) {
                const u16* kp = Kb + ((size_t)bh * 4096 + key0 + nt * 16 + colq) * 64 + quad * 8;
                bf16x8 b0 = *(const bf16x8*)kp;
                bf16x8 b1 = *(const bf16x8*)(kp + 32);
                f32x4 z = {0.f, 0.f, 0.f, 0.f};
                z = __builtin_amdgcn_mfma_f32_16x16x32_bf16(aq0, b0, z, 0, 0, 0);
                z = __builtin_amdgcn_mfma_f32_16x16x32_bf16(aq1, b1, z, 0, 0, 0);
                sc[j] = z;
            }
        }
        // chunk row-max
        float mc[4];
#pragma unroll
        for (int i = 0; i < 4; ++i) mc[i] = -3.0e38f;
#pragma unroll
        for (int j = 0; j < 12; ++j) {
            const int nt = c * 12 + j;
            if (nt >= lo && nt < hi)
#pragma unroll
                for (int i = 0; i < 4; ++i) mc[i] = fmaxf(mc[i], sc[j][i]);
        }
#pragma unroll
        for (int i = 0; i < 4; ++i)
#pragma unroll
            for (int m = 8; m >= 1; m >>= 1) mc[i] = fmaxf(mc[i], __shfl_xor(mc[i], m, 64));
        // online-softmax update
        float a_i[4], psum[4];
#pragma unroll
        for (int i = 0; i < 4; ++i) {
            const float mn = fmaxf(m_i[i], mc[i]);
            a_i[i] = __expf((m_i[i] - mn) * 0.125f);   // scale = hd^-0.5
            m_i[i] = mn;
            psum[i] = 0.f;
        }
#pragma unroll
        for (int j = 0; j < 12; ++j) {
            const int nt = c * 12 + j;
            if (nt >= lo && nt < hi) {
#pragma unroll
                for (int i = 0; i < 4; ++i) {
                    const float p = __expf((sc[j][i] - m_i[i]) * 0.125f);
                    psum[i] += p;
                    Psw[(quad * 4 + i) * 200 + j * 16 + colq] = f2bf(p);
                }
            }
        }
#pragma unroll
        for (int i = 0; i < 4; ++i)
#pragma unroll
            for (int m = 8; m >= 1; m >>= 1) psum[i] += __shfl_xor(psum[i], m, 64);
#pragma unroll
        for (int i = 0; i < 4; ++i) l_i[i] = l_i[i] * a_i[i] + psum[i];
#pragma unroll
        for (int dt = 0; dt < 4; ++dt)
#pragma unroll
            for (int i = 0; i < 4; ++i) o[dt][i] *= a_i[i];
        // PV over this chunk (Ps is wave-private: no barrier, lgkm ordering)
        const int klo = (lo - c * 12) >> 1;
        const int khi = (hi - c * 12) >> 1;
#pragma unroll
        for (int k6 = 0; k6 < 6; ++k6) {
            if (k6 >= klo && k6 < khi) {
                bf16x8 ap = *(const bf16x8*)(Psw + colq * 200 + k6 * 32 + quad * 8);
                const int kk = key0 + (c * 6 + k6) * 32 + quad * 8;
#pragma unroll
                for (int dt = 0; dt < 4; ++dt) {
                    const u16* vp = Vt + ((size_t)bh * 64 + dt * 16 + colq) * 4096 + kk;
                    bf16x8 bv = *(const bf16x8*)vp;
                    o[dt] = __builtin_amdgcn_mfma_f32_16x16x32_bf16(ap, bv, o[dt], 0, 0, 0);
                }
            }
        }
    }

    const int bb = bh >> 4, hh = bh & 15;
#pragma unroll
    for (int i = 0; i < 4; ++i) {
        const float inv = 1.0f / fmaxf(l_i[i], 1e-20f);
        const int t = qrow0 + quad * 4 + i;
        u16* op = out + ((size_t)(bb * 4096 + t)) * 1024 + hh * 64;
#pragma unroll
        for (int dt = 0; dt < 4; ++dt) op[dt * 16 + colq] = f2bf(o[dt][i] * inv);
    }
}

// ---------------------------------------------------------------------------
extern "C" void kernel_launch(void* const* d_in, const int* in_sizes, int n_in,
                              void* d_out, int out_size, void* d_ws, size_t ws_size,
                              hipStream_t stream)
{
    const float* x      = (const float*)d_in[0];
    const float* ln1_w  = (const float*)d_in[1];
    const float* ln1_b  = (const float*)d_in[2];
    const float* qkv_w  = (const float*)d_in[3];
    const float* qkv_b  = (const float*)d_in[4];
    const float* proj_w = (const float*)d_in[5];
    const float* proj_b = (const float*)d_in[6];
    const float* ln2_w  = (const float*)d_in[7];
    const float* ln2_b  = (const float*)d_in[8];
    const float* fc1_w  = (const float*)d_in[9];
    const float* fc1_b  = (const float*)d_in[10];
    const float* fc2_w  = (const float*)d_in[11];
    const float* fc2_b  = (const float*)d_in[12];
    float* outp = (float*)d_out;

    if (ws_size < 134217728u) return;
    char* ws = (char*)d_ws;
    // ws regions (33.5 MB each):
    u16* R0 = (u16*)(ws);               // all bf16 weights (25.2 MB)
    u16* R1 = (u16*)(ws + 33554432);    // Q  -> x2
    u16* R2 = (u16*)(ws + 67108864);    // K  -> h (with R3, 67 MB contiguous)
    u16* R3 = (u16*)(ws + 100663296);   // Vt -> h upper half
    // d_out doubles as scratch:
    u16* xnc    = (u16*)d_out;                        // xn   @ d_out[0    : 33.5M)
    u16* attn_o = (u16*)((char*)d_out + 33554432);    // attn @ d_out[33.5M: 67M), later yn

    u16* qkvwb = R0;                    // 3,145,728 el
    u16* projwb = R0 + 3145728;         // 1,048,576 el
    u16* fc1wb = R0 + 4194304;          // 4,194,304 el
    u16* fc2wb = R0 + 8388608;          // 4,194,304 el
    u16* Qb = R1, *Kb = R2, *Vtb = R3;
    u16* x2 = R1;                       // Q dead after attn
    u16* yn = attn_o;                   // attn_o dead after proj
    u16* hb = R2;                       // K,Vt dead after attn: 67 MB contiguous

    // 1. weights f32 -> bf16
    cvt_kernel<<<3072, 256, 0, stream>>>(qkv_w, qkvwb, 3145728);
    cvt_kernel<<<1024, 256, 0, stream>>>(proj_w, projwb, 1048576);
    cvt_kernel<<<4096, 256, 0, stream>>>(fc1_w, fc1wb, 4194304);
    cvt_kernel<<<4096, 256, 0, stream>>>(fc2_w, fc2wb, 4194304);
    // 2. LN1: x -> xn (full 16384 rows)
    ln_kernel<true><<<4096, 256, 0, stream>>>(x, ln1_w, ln1_b, xnc);
    // 3. qkv GEMM + scatter (single dispatch, 3072 blocks)
    gemm_bt<0, 0, false><<<dim3(24, 128), 256, 0, stream>>>(xnc, qkvwb, qkv_b, nullptr, nullptr,
                                                            Qb, Kb, Vtb, 16384, 3072, 1024, 0);
    // 4. local attention -> attn_o
    attn_kernel<<<4096, 256, 0, stream>>>(Qb, Kb, Vtb, attn_o);
    // 5. proj + residual(x, f32) -> x2 (bf16)
    gemm_bt<1, 1, false><<<dim3(8, 128), 256, 0, stream>>>(attn_o, projwb, proj_b, x, nullptr,
                                                           x2, nullptr, nullptr, 16384, 1024, 1024, 0);
    // 6. LN2: x2 -> yn (overwrites attn_o region; full 16384 rows)
    ln_kernel<false><<<4096, 256, 0, stream>>>(x2, ln2_w, ln2_b, yn);
    // 7. FFN in 2 M-chunks of 8192 rows; h (67 MB) in R2+R3.
    //    fc2 chunk c writes d_out bytes [c*33.5M, +33.5M) f32 — yn bytes needed by
    //    fc1 chunk 1 live at [33.5M+16.8M..] and are only clobbered by fc2 chunk 1,
    //    which runs after fc1 chunk 1 (stream-ordered). Safe.
    for (int ci = 0; ci < 2; ++ci) {
        const size_t off = (size_t)ci * 8192 * 1024;
        gemm_bt<2, 0, false><<<dim3(32, 64), 256, 0, stream>>>(yn + off, fc1wb, fc1_b, nullptr, nullptr,
                                                               hb, nullptr, nullptr, 8192, 4096, 1024, 0);
        gemm_bt<1, 2, true><<<dim3(8, 64), 256, 0, stream>>>(hb, fc2wb, fc2_b, nullptr, x2 + off,
                                                             outp + off, nullptr, nullptr, 8192, 1024, 4096, 0);
    }
}